// Round 4
// baseline (888.488 us; speedup 1.0000x reference)
//
#include <hip/hip_runtime.h>

typedef float v2f __attribute__((ext_vector_type(2)));
typedef float v4f __attribute__((ext_vector_type(4)));

#define T_STEPS 2048
#define BATCH   2
#define IDIM    40
#define HDIM    44
#define GDIM    176      // 4*H
#define ADIM    262144
#define EDIM    88       // 2*H

__device__ __forceinline__ float fast_sigmoid(float x) {
    return __builtin_amdgcn_rcpf(1.0f + __expf(-x));
}
__device__ __forceinline__ float fast_tanh(float x) {
    // tanh(x) = 1 - 2/(exp(2x)+1); saturates correctly
    return 1.0f - 2.0f * __builtin_amdgcn_rcpf(__expf(2.0f * x) + 1.0f);
}
// packed fma with UNIFORM h operand held in an SGPR pair (1 sgpr read: legal)
__device__ __forceinline__ void pk_fma_s(v2f& acc, v2f w, unsigned long long h) {
    asm("v_pk_fma_f32 %0, %1, %2, %0" : "+v"(acc) : "v"(w), "s"(h));
}

// K1: xproj[t][b][gi] = b_ih[gi] + b_hh[gi] + sum_i x[t][b][i] * W_ih[gi][i]
__global__ __launch_bounds__(192) void xproj_kernel(
    const float* __restrict__ x,      // [T][B][40]
    const float* __restrict__ W_ih,   // [176][40]
    const float* __restrict__ b_ih,   // [176]
    const float* __restrict__ b_hh,   // [176]
    float* __restrict__ xproj)        // [T][B][176]
{
    const int tb = blockIdx.x;        // t*B + b
    const int gi = threadIdx.x;
    __shared__ __align__(16) float xs[IDIM];
    if (threadIdx.x < IDIM) xs[threadIdx.x] = x[(size_t)tb * IDIM + threadIdx.x];
    __syncthreads();
    if (gi < GDIM) {
        const float* wr = W_ih + gi * IDIM;
        float a0 = 0.f, a1 = 0.f;
        #pragma unroll
        for (int i = 0; i < IDIM; i += 4) {
            float4 wv = *(const float4*)&wr[i];
            float4 xv = *(const float4*)&xs[i];
            a0 += wv.x * xv.x + wv.z * xv.z;
            a1 += wv.y * xv.y + wv.w * xv.w;
        }
        xproj[(size_t)tb * GDIM + gi] = a0 + a1 + b_ih[gi] + b_hh[gi];
    }
}

// K2: serial LSTM, ONE WAVE per batch, ZERO LDS.
// Lane j owns h[j], c[j] and gate rows {j, 44+j, 88+j, 132+j} of W_hh in
// VGPRs (176). The h vector is uniform-per-step and lives in 22 SGPR PAIRS,
// rebuilt each step with 44 v_readlane. v_pk_fma_f32 reads h from SGPRs.
// VGPR demand ~195 < 256 -> no AGPR shuttling.
__global__ __launch_bounds__(64, 1) void lstm_kernel(
    const float* __restrict__ xproj,  // [T][B][176]
    const float* __restrict__ h0,     // [1][B][44]
    const float* __restrict__ c0,     // [1][B][44]
    const float* __restrict__ W_hh,   // [176][44]
    const float* __restrict__ W_v,    // [1][128]
    const float* __restrict__ b_v,    // [1]
    float* __restrict__ base_out)     // [B]
{
    const int b = blockIdx.x;
    const int j = threadIdx.x;          // 0..63; lanes >= 44 are passengers
    const int jj = (j < HDIM) ? j : (HDIM - 1);   // clamped (no OOB)

    // Per-lane weight rows in registers (4 x 44 = 176 VGPRs as 88 v2f pairs)
    v2f wi[22], wf[22], wg[22], wo[22];
    {
        const float* ri = W_hh + (size_t)jj * HDIM;
        const float* rf = W_hh + (size_t)(HDIM + jj) * HDIM;
        const float* rg = W_hh + (size_t)(2 * HDIM + jj) * HDIM;
        const float* ro = W_hh + (size_t)(3 * HDIM + jj) * HDIM;
        #pragma unroll
        for (int k = 0; k < 22; ++k) {
            wi[k] = ((const v2f*)ri)[k];
            wf[k] = ((const v2f*)rf)[k];
            wg[k] = ((const v2f*)rg)[k];
            wo[k] = ((const v2f*)ro)[k];
        }
    }

    float c = c0[b * HDIM + jj];

    // h in SGPR pairs (uniform address -> s_load)
    unsigned long long h64[22];
    {
        const unsigned long long* hp0 = (const unsigned long long*)(h0 + b * HDIM);
        #pragma unroll
        for (int k = 0; k < 22; ++k) h64[k] = hp0[k];
    }

    const float* xp = xproj + (size_t)b * GDIM;   // step stride = B*GDIM
    float xc0 = xp[jj], xc1 = xp[HDIM + jj], xc2 = xp[2 * HDIM + jj], xc3 = xp[3 * HDIM + jj];
    float hval = 0.f;

    #pragma unroll 1
    for (int step = 0; step < T_STEPS; ++step) {
        // prefetch next step's xproj (L2-resident, hidden under FMAs)
        const int nstep = (step + 1 < T_STEPS) ? step + 1 : step;
        const float* xn = xp + (size_t)nstep * (BATCH * GDIM);
        float xn0 = xn[jj], xn1 = xn[HDIM + jj], xn2 = xn[2 * HDIM + jj], xn3 = xn[3 * HDIM + jj];

        // 4 gate dot-products; h sourced from SGPR pairs
        v2f ai = (v2f)(0.f), af = (v2f)(0.f), ag = (v2f)(0.f), ao = (v2f)(0.f);
        #pragma unroll
        for (int k = 0; k < 22; ++k) {
            pk_fma_s(ai, wi[k], h64[k]);
            pk_fma_s(af, wf[k], h64[k]);
            pk_fma_s(ag, wg[k], h64[k]);
            pk_fma_s(ao, wo[k], h64[k]);
        }
        float gi = ai.x + ai.y + xc0;
        float gf = af.x + af.y + xc1;
        float gg = ag.x + ag.y + xc2;
        float go = ao.x + ao.y + xc3;

        float s_i = fast_sigmoid(gi);
        float s_f = fast_sigmoid(gf);
        float s_o = fast_sigmoid(go);
        float t_g = fast_tanh(gg);
        c = s_f * c + s_i * t_g;
        hval = s_o * fast_tanh(c);

        // broadcast new h into SGPR pairs: 44 readlanes, no LDS
        {
            int hb = __float_as_int(hval);
            #pragma unroll
            for (int k = 0; k < 22; ++k) {
                unsigned int lo = (unsigned int)__builtin_amdgcn_readlane(hb, 2 * k);
                unsigned int hi = (unsigned int)__builtin_amdgcn_readlane(hb, 2 * k + 1);
                h64[k] = ((unsigned long long)hi << 32) | lo;
            }
        }
        xc0 = xn0; xc1 = xn1; xc2 = xn2; xc3 = xn3;
    }

    // epilogue: base[b] = sum_j h[j]*Wv[j] + c[j]*Wv[44+j] + b_v
    float p = 0.f;
    if (j < HDIM) p = hval * W_v[j] + c * W_v[HDIM + j];
    #pragma unroll
    for (int off = 32; off; off >>= 1) p += __shfl_down(p, off);
    if (j == 0) base_out[b] = p + b_v[0];
}

// K3: out[b][a] = (a < len[b]) ? base[b] + action[b][a][:].w_a : 0
__global__ __launch_bounds__(256) void action_kernel(
    const float* __restrict__ action,     // [B][A][40]
    const int*   __restrict__ act_length, // [B]
    const float* __restrict__ W_v,        // [1][128]; w_a = W_v[88..127]
    const float* __restrict__ base,       // [B]
    float* __restrict__ out)              // [B][A]
{
    const int idx = blockIdx.x * 256 + threadIdx.x;   // 0 .. B*A-1
    const int b = idx >> 18;                          // A = 2^18
    const int a = idx & (ADIM - 1);
    if (a >= act_length[b]) { out[idx] = 0.f; return; }
    const float* row = action + (size_t)idx * IDIM;
    float a0 = 0.f, a1 = 0.f;
    #pragma unroll
    for (int i = 0; i < IDIM; i += 4) {
        float4 av = *(const float4*)&row[i];
        a0 += av.x * W_v[EDIM + i + 0] + av.z * W_v[EDIM + i + 2];
        a1 += av.y * W_v[EDIM + i + 1] + av.w * W_v[EDIM + i + 3];
    }
    out[idx] = base[b] + a0 + a1;
}

extern "C" void kernel_launch(void* const* d_in, const int* in_sizes, int n_in,
                              void* d_out, int out_size, void* d_ws, size_t ws_size,
                              hipStream_t stream) {
    const float* x        = (const float*)d_in[0];
    const float* h0       = (const float*)d_in[1];
    const float* c0       = (const float*)d_in[2];
    const float* action   = (const float*)d_in[3];
    const int*   act_len  = (const int*)  d_in[4];
    const float* W_ih     = (const float*)d_in[5];
    const float* W_hh     = (const float*)d_in[6];
    const float* b_ih     = (const float*)d_in[7];
    const float* b_hh     = (const float*)d_in[8];
    const float* W_v      = (const float*)d_in[9];
    const float* b_v      = (const float*)d_in[10];
    float* out = (float*)d_out;

    float* xproj = (float*)d_ws;                                   // T*B*176 floats
    float* base  = xproj + (size_t)T_STEPS * BATCH * GDIM;         // B floats

    xproj_kernel<<<dim3(T_STEPS * BATCH), dim3(192), 0, stream>>>(
        x, W_ih, b_ih, b_hh, xproj);
    lstm_kernel<<<dim3(BATCH), dim3(64), 0, stream>>>(
        xproj, h0, c0, W_hh, W_v, b_v, base);
    action_kernel<<<dim3((BATCH * ADIM) / 256), dim3(256), 0, stream>>>(
        action, act_len, W_v, base, out);
}

// Round 5
// 732.626 us; speedup vs baseline: 1.2127x; 1.2127x over previous
//
#include <hip/hip_runtime.h>

typedef float v2f __attribute__((ext_vector_type(2)));
typedef float v4f __attribute__((ext_vector_type(4)));

#define T_STEPS 2048
#define BATCH   2
#define IDIM    40
#define HDIM    44
#define GDIM    176      // 4*H
#define ADIM    262144
#define EDIM    88       // 2*H

__device__ __forceinline__ float fast_sigmoid(float x) {
    return __builtin_amdgcn_rcpf(1.0f + __expf(-x));
}
__device__ __forceinline__ float fast_tanh(float x) {
    // tanh(x) = 1 - 2/(exp(2x)+1); saturates correctly
    return 1.0f - 2.0f * __builtin_amdgcn_rcpf(__expf(2.0f * x) + 1.0f);
}

// K1: xproj[t][b][gi] = b_ih[gi] + b_hh[gi] + sum_i x[t][b][i] * W_ih[gi][i]
__global__ __launch_bounds__(192) void xproj_kernel(
    const float* __restrict__ x,      // [T][B][40]
    const float* __restrict__ W_ih,   // [176][40]
    const float* __restrict__ b_ih,   // [176]
    const float* __restrict__ b_hh,   // [176]
    float* __restrict__ xproj)        // [T][B][176]
{
    const int tb = blockIdx.x;        // t*B + b
    const int gi = threadIdx.x;
    __shared__ __align__(16) float xs[IDIM];
    if (threadIdx.x < IDIM) xs[threadIdx.x] = x[(size_t)tb * IDIM + threadIdx.x];
    __syncthreads();
    if (gi < GDIM) {
        const float* wr = W_ih + gi * IDIM;
        float a0 = 0.f, a1 = 0.f;
        #pragma unroll
        for (int i = 0; i < IDIM; i += 4) {
            float4 wv = *(const float4*)&wr[i];
            float4 xv = *(const float4*)&xs[i];
            a0 += wv.x * xv.x + wv.z * xv.z;
            a1 += wv.y * xv.y + wv.w * xv.w;
        }
        xproj[(size_t)tb * GDIM + gi] = a0 + a1 + b_ih[gi] + b_hh[gi];
    }
}

// K2: serial LSTM, ONE WAVE per batch. Lane j owns h[j], c[j] and gate rows
// {j, 44+j, 88+j, 132+j} of W_hh in registers. h broadcast via LDS.
// PURE C inner loop (no inline asm) + waves_per_eu(1,1): give the register
// allocator a full 256-arch-VGPR budget and no reason to park weights in
// AGPRs (rounds 1-3 all suffered v_accvgpr shuttling, ~124 arch VGPRs).
__global__ __launch_bounds__(64)
__attribute__((amdgpu_waves_per_eu(1, 1)))
void lstm_kernel(
    const float* __restrict__ xproj,  // [T][B][176]
    const float* __restrict__ h0,     // [1][B][44]
    const float* __restrict__ c0,     // [1][B][44]
    const float* __restrict__ W_hh,   // [176][44]
    const float* __restrict__ W_v,    // [1][128]
    const float* __restrict__ b_v,    // [1]
    float* __restrict__ base_out)     // [B]
{
    const int b = blockIdx.x;
    const int j = threadIdx.x;          // 0..63; lanes >= 44 are passengers
    const int jj = (j < HDIM) ? j : (HDIM - 1);   // clamped (no OOB)

    __shared__ __align__(16) float h_sh[HDIM];

    // Per-lane weight rows in registers (4 x 44 = 176 floats as 88 v2f pairs)
    v2f wi[22], wf[22], wg[22], wo[22];
    {
        const float* ri = W_hh + (size_t)jj * HDIM;
        const float* rf = W_hh + (size_t)(HDIM + jj) * HDIM;
        const float* rg = W_hh + (size_t)(2 * HDIM + jj) * HDIM;
        const float* ro = W_hh + (size_t)(3 * HDIM + jj) * HDIM;
        #pragma unroll
        for (int k = 0; k < 22; ++k) {
            wi[k] = ((const v2f*)ri)[k];
            wf[k] = ((const v2f*)rf)[k];
            wg[k] = ((const v2f*)rg)[k];
            wo[k] = ((const v2f*)ro)[k];
        }
    }

    float c = c0[b * HDIM + jj];
    if (j < HDIM) h_sh[j] = h0[b * HDIM + j];
    __syncthreads();

    // broadcast-read full h into registers (all lanes)
    v2f hp[22];
    #pragma unroll
    for (int k = 0; k < 11; ++k) {
        v4f t = ((const v4f*)h_sh)[k];
        hp[2 * k]     = __builtin_shufflevector(t, t, 0, 1);
        hp[2 * k + 1] = __builtin_shufflevector(t, t, 2, 3);
    }

    const float* xp = xproj + (size_t)b * GDIM;   // step stride = B*GDIM
    float xc0 = xp[jj], xc1 = xp[HDIM + jj], xc2 = xp[2 * HDIM + jj], xc3 = xp[3 * HDIM + jj];
    float hval = 0.f;

    #pragma unroll 1
    for (int step = 0; step < T_STEPS; ++step) {
        // prefetch next step's xproj (L2-resident, hidden under FMAs)
        const int nstep = (step + 1 < T_STEPS) ? step + 1 : step;
        const float* xn = xp + (size_t)nstep * (BATCH * GDIM);
        float xn0 = xn[jj], xn1 = xn[HDIM + jj], xn2 = xn[2 * HDIM + jj], xn3 = xn[3 * HDIM + jj];

        // 4 gate dot-products, one packed accumulator chain per gate (pure C)
        v2f ai = (v2f)(0.f), af = (v2f)(0.f), ag = (v2f)(0.f), ao = (v2f)(0.f);
        #pragma unroll
        for (int k = 0; k < 22; ++k) {
            ai = __builtin_elementwise_fma(wi[k], hp[k], ai);
            af = __builtin_elementwise_fma(wf[k], hp[k], af);
            ag = __builtin_elementwise_fma(wg[k], hp[k], ag);
            ao = __builtin_elementwise_fma(wo[k], hp[k], ao);
        }
        float gi = ai.x + ai.y + xc0;
        float gf = af.x + af.y + xc1;
        float gg = ag.x + ag.y + xc2;
        float go = ao.x + ao.y + xc3;

        float s_i = fast_sigmoid(gi);
        float s_f = fast_sigmoid(gf);
        float s_o = fast_sigmoid(go);
        float t_g = fast_tanh(gg);
        c = s_f * c + s_i * t_g;
        hval = s_o * fast_tanh(c);

        if (j < HDIM) h_sh[j] = hval;
        __syncthreads();

        #pragma unroll
        for (int k = 0; k < 11; ++k) {
            v4f t = ((const v4f*)h_sh)[k];
            hp[2 * k]     = __builtin_shufflevector(t, t, 0, 1);
            hp[2 * k + 1] = __builtin_shufflevector(t, t, 2, 3);
        }
        xc0 = xn0; xc1 = xn1; xc2 = xn2; xc3 = xn3;
    }

    // epilogue: base[b] = sum_j h[j]*Wv[j] + c[j]*Wv[44+j] + b_v
    float p = 0.f;
    if (j < HDIM) p = hval * W_v[j] + c * W_v[HDIM + j];
    #pragma unroll
    for (int off = 32; off; off >>= 1) p += __shfl_down(p, off);
    if (j == 0) base_out[b] = p + b_v[0];
}

// K3: out[b][a] = (a < len[b]) ? base[b] + action[b][a][:].w_a : 0
__global__ __launch_bounds__(256) void action_kernel(
    const float* __restrict__ action,     // [B][A][40]
    const int*   __restrict__ act_length, // [B]
    const float* __restrict__ W_v,        // [1][128]; w_a = W_v[88..127]
    const float* __restrict__ base,       // [B]
    float* __restrict__ out)              // [B][A]
{
    const int idx = blockIdx.x * 256 + threadIdx.x;   // 0 .. B*A-1
    const int b = idx >> 18;                          // A = 2^18
    const int a = idx & (ADIM - 1);
    if (a >= act_length[b]) { out[idx] = 0.f; return; }
    const float* row = action + (size_t)idx * IDIM;
    float a0 = 0.f, a1 = 0.f;
    #pragma unroll
    for (int i = 0; i < IDIM; i += 4) {
        float4 av = *(const float4*)&row[i];
        a0 += av.x * W_v[EDIM + i + 0] + av.z * W_v[EDIM + i + 2];
        a1 += av.y * W_v[EDIM + i + 1] + av.w * W_v[EDIM + i + 3];
    }
    out[idx] = base[b] + a0 + a1;
}

extern "C" void kernel_launch(void* const* d_in, const int* in_sizes, int n_in,
                              void* d_out, int out_size, void* d_ws, size_t ws_size,
                              hipStream_t stream) {
    const float* x        = (const float*)d_in[0];
    const float* h0       = (const float*)d_in[1];
    const float* c0       = (const float*)d_in[2];
    const float* action   = (const float*)d_in[3];
    const int*   act_len  = (const int*)  d_in[4];
    const float* W_ih     = (const float*)d_in[5];
    const float* W_hh     = (const float*)d_in[6];
    const float* b_ih     = (const float*)d_in[7];
    const float* b_hh     = (const float*)d_in[8];
    const float* W_v      = (const float*)d_in[9];
    const float* b_v      = (const float*)d_in[10];
    float* out = (float*)d_out;

    float* xproj = (float*)d_ws;                                   // T*B*176 floats
    float* base  = xproj + (size_t)T_STEPS * BATCH * GDIM;         // B floats

    xproj_kernel<<<dim3(T_STEPS * BATCH), dim3(192), 0, stream>>>(
        x, W_ih, b_ih, b_hh, xproj);
    lstm_kernel<<<dim3(BATCH), dim3(64), 0, stream>>>(
        xproj, h0, c0, W_hh, W_v, b_v, base);
    action_kernel<<<dim3((BATCH * ADIM) / 256), dim3(256), 0, stream>>>(
        action, act_len, W_v, base, out);
}